// Round 3
// baseline (280.148 us; speedup 1.0000x reference)
//
#include <hip/hip_runtime.h>
#include <hip/hip_bf16.h>
#include <math.h>

// HGNNExpertCoupler: algebraically collapsed.
//   all_pairs hypergraph => M = (6I+J)/14, doubly stochastic; mean-pool kills it:
//   out = LN(gelu( meanE(x) @ (Wc*W2*W1)^T + Wc*(W2*b1+b2)+cb ))
// Kernels: pool(mean over E, ->bf16) | weight prep (cast/transpose, 2 small
// MFMA GEMMs, bias matvecs) | main MFMA GEMM + fused gelu+LayerNorm epilogue.

#define DD 512
#define NTOK 8192  // B*L = 8*1024

typedef short s16x8 __attribute__((ext_vector_type(8)));
typedef short s16x4 __attribute__((ext_vector_type(4)));
typedef float f32x4 __attribute__((ext_vector_type(4)));

static __device__ __forceinline__ short f2bf(float x) {
  unsigned u = __builtin_bit_cast(unsigned, x);
  unsigned r = (u + 0x7fffu + ((u >> 16) & 1u)) >> 16;
  return (short)r;
}

// ---------------- pool: g[n,d] = mean_e x[n,e,d], write bf16 -----------------
__global__ __launch_bounds__(256) void pool_kernel(const float* __restrict__ in,
                                                   short* __restrict__ gbf) {
  const int total = NTOK * (DD / 4);  // 1,048,576 float4 outputs
  for (int i = blockIdx.x * blockDim.x + threadIdx.x; i < total;
       i += gridDim.x * blockDim.x) {
    int n = i >> 7;
    int d4 = (i & 127) << 2;
    const float* p = in + (size_t)n * (8 * DD) + d4;
    f32x4 s = {0.f, 0.f, 0.f, 0.f};
#pragma unroll
    for (int e = 0; e < 8; ++e) s += *(const f32x4*)(p + e * DD);
    s *= 0.125f;
    s16x4 o;
    o[0] = f2bf(s[0]); o[1] = f2bf(s[1]); o[2] = f2bf(s[2]); o[3] = f2bf(s[3]);
    *(s16x4*)(gbf + (size_t)n * DD + d4) = o;
  }
}

// ---------------- straight casts: W2, Wc -> bf16 -----------------
__global__ __launch_bounds__(256) void cast2_kernel(const float* __restrict__ w2,
                                                    const float* __restrict__ wc,
                                                    short* __restrict__ w2b,
                                                    short* __restrict__ wcb) {
  int i = blockIdx.x * blockDim.x + threadIdx.x;  // 131072 threads, 4 elems each
  const float* src = (i < 65536) ? w2 : wc;
  short* dst = (i < 65536) ? w2b : wcb;
  int j = (i & 65535) << 2;
  f32x4 v = *(const f32x4*)(src + j);
  s16x4 o;
  o[0] = f2bf(v[0]); o[1] = f2bf(v[1]); o[2] = f2bf(v[2]); o[3] = f2bf(v[3]);
  *(s16x4*)(dst + j) = o;
}

// ---------------- transpose-cast: W1T_bf[c][r] = bf16(W1[r][c]) -------------
__global__ __launch_bounds__(256) void casttr_kernel(const float* __restrict__ w1,
                                                     short* __restrict__ w1t) {
  __shared__ float t[32][33];
  int bx = blockIdx.x & 15, by = blockIdx.x >> 4;
  int tx = threadIdx.x & 31, ty8 = threadIdx.x >> 5;  // 32 x 8
  int r0 = by * 32, c0 = bx * 32;
#pragma unroll
  for (int j = 0; j < 4; ++j) {
    int r = ty8 * 4 + j;
    t[r][tx] = w1[(size_t)(r0 + r) * DD + c0 + tx];
  }
  __syncthreads();
#pragma unroll
  for (int j = 0; j < 4; ++j) {
    int r = ty8 * 4 + j;
    w1t[(size_t)(c0 + r) * DD + r0 + tx] = f2bf(t[tx][r]);
  }
}

// ---------------- matvec: outv[i] = add[i] + sum_k M[i,k] v[k] --------------
__global__ __launch_bounds__(256) void mv_kernel(const float* __restrict__ M,
                                                 const float* __restrict__ v,
                                                 const float* __restrict__ add,
                                                 float* __restrict__ outv) {
  int w = (blockIdx.x * blockDim.x + threadIdx.x) >> 6;  // global wave id = row
  int l = threadIdx.x & 63;
  if (w >= DD) return;
  float s = 0.f;
  for (int k = l; k < DD; k += 64) s += M[(size_t)w * DD + k] * v[k];
#pragma unroll
  for (int m = 32; m; m >>= 1) s += __shfl_xor(s, m);
  if (l == 0) outv[w] = s + add[w];
}

// -------- small NT GEMM (512x512x512): Out[m,n] = sum_k A[m,k]*B[n,k] -------
// A,B,Out bf16 row-major (K-contiguous). 64x64 tiles, 64 blocks, 4 waves.
__global__ __launch_bounds__(256) void wgemm_kernel(const short* __restrict__ A,
                                                    const short* __restrict__ B,
                                                    short* __restrict__ Out) {
  int w = threadIdx.x >> 6, l = threadIdx.x & 63;
  int lr = l & 15, lg = l >> 4;
  int m0 = (blockIdx.x >> 3) * 64 + w * 16;
  int n0 = (blockIdx.x & 7) * 64;
  f32x4 acc[4] = {};
  const short* ap = A + (size_t)(m0 + lr) * DD + 8 * lg;
  const short* bp = B + (size_t)(n0 + lr) * DD + 8 * lg;
#pragma unroll
  for (int k0 = 0; k0 < DD; k0 += 32) {
    s16x8 a = *(const s16x8*)(ap + k0);
#pragma unroll
    for (int f = 0; f < 4; ++f) {
      s16x8 b = *(const s16x8*)(bp + (size_t)f * 16 * DD + k0);
      acc[f] = __builtin_amdgcn_mfma_f32_16x16x32_bf16(a, b, acc[f], 0, 0, 0);
    }
  }
#pragma unroll
  for (int f = 0; f < 4; ++f)
#pragma unroll
    for (int r = 0; r < 4; ++r)
      Out[(size_t)(m0 + lg * 4 + r) * DD + n0 + f * 16 + lr] = f2bf(acc[f][r]);
}

// ------- main: pre = g @ Wcomb^T + cbias; out = LN(gelu(pre)) ---------------
// 32 tokens x 512 outs per block; 4 waves, wave tile 32x128. A in swizzled LDS.
__global__ __launch_bounds__(256) void main_kernel(
    const short* __restrict__ gbf, const short* __restrict__ wcomb,
    const float* __restrict__ cbias, const float* __restrict__ gamma,
    const float* __restrict__ beta, float* __restrict__ out) {
  __shared__ short As[32 * DD];      // 32 KB, XOR-swizzled rows
  __shared__ float red[32][4][2];    // per-row per-wave {sum, sumsq}
  int tid = threadIdx.x;
  int w = tid >> 6, l = tid & 63;
  int lr = l & 15, lg = l >> 4;
  int m0 = blockIdx.x * 32;

  // stage A tile (32 rows x 512 cols bf16, contiguous 32KB in global):
  // linear global read, swizzled ds_write: byte ^= ((row&7)<<4)
  {
    const char* gs = (const char*)(gbf + (size_t)m0 * DD);
    char* ls = (char*)As;
#pragma unroll
    for (int j = 0; j < 8; ++j) {
      int ci = tid + 256 * j;
      int row = ci >> 6;
      int bo = (ci & 63) << 4;
      s16x8 v = *(const s16x8*)(gs + row * 1024 + bo);
      *(s16x8*)(ls + row * 1024 + (bo ^ ((row & 7) << 4))) = v;
    }
  }
  __syncthreads();

  f32x4 acc[2][8] = {};
  const short* bbase = wcomb + (size_t)(w * 128 + lr) * DD + 8 * lg;
  const char* lsc = (const char*)As;
  for (int k0 = 0; k0 < DD; k0 += 32) {
    int kb = (k0 + 8 * lg) * 2;
    int row0 = lr, row1 = 16 + lr;
    s16x8 a0 = *(const s16x8*)(lsc + row0 * 1024 + (kb ^ ((row0 & 7) << 4)));
    s16x8 a1 = *(const s16x8*)(lsc + row1 * 1024 + (kb ^ ((row1 & 7) << 4)));
#pragma unroll
    for (int f = 0; f < 8; ++f) {
      s16x8 b = *(const s16x8*)(bbase + (size_t)f * 16 * DD + k0);
      acc[0][f] = __builtin_amdgcn_mfma_f32_16x16x32_bf16(a0, b, acc[0][f], 0, 0, 0);
      acc[1][f] = __builtin_amdgcn_mfma_f32_16x16x32_bf16(a1, b, acc[1][f], 0, 0, 0);
    }
  }

  // epilogue: +cbias, exact gelu, per-row LN across the 512 outs
  int cbase = w * 128 + lr;
  float s1[2][4] = {}, s2[2][4] = {};
#pragma unroll
  for (int mi = 0; mi < 2; ++mi)
#pragma unroll
    for (int f = 0; f < 8; ++f) {
      float cb = cbias[cbase + f * 16];
#pragma unroll
      for (int r = 0; r < 4; ++r) {
        float x = acc[mi][f][r] + cb;
        float z = 0.5f * x * (1.0f + erff(x * 0.70710678118f));
        acc[mi][f][r] = z;  // reuse regs to hold z
        s1[mi][r] += z;
        s2[mi][r] += z * z;
      }
    }
  // reduce across the 16 lanes sharing the same rows (lane&15 varies = cols)
#pragma unroll
  for (int m = 1; m < 16; m <<= 1)
#pragma unroll
    for (int mi = 0; mi < 2; ++mi)
#pragma unroll
      for (int r = 0; r < 4; ++r) {
        s1[mi][r] += __shfl_xor(s1[mi][r], m);
        s2[mi][r] += __shfl_xor(s2[mi][r], m);
      }
  if (lr == 0) {
#pragma unroll
    for (int mi = 0; mi < 2; ++mi)
#pragma unroll
      for (int r = 0; r < 4; ++r) {
        int row = mi * 16 + lg * 4 + r;
        red[row][w][0] = s1[mi][r];
        red[row][w][1] = s2[mi][r];
      }
  }
  __syncthreads();
#pragma unroll
  for (int mi = 0; mi < 2; ++mi)
#pragma unroll
    for (int r = 0; r < 4; ++r) {
      int row = mi * 16 + lg * 4 + r;
      float t1 = red[row][0][0] + red[row][1][0] + red[row][2][0] + red[row][3][0];
      float t2 = red[row][0][1] + red[row][1][1] + red[row][2][1] + red[row][3][1];
      float mu = t1 * (1.0f / 512.0f);
      float var = t2 * (1.0f / 512.0f) - mu * mu;
      float rs = rsqrtf(var + 1e-5f);
      float* op = out + (size_t)(m0 + row) * DD;
#pragma unroll
      for (int f = 0; f < 8; ++f) {
        int c = cbase + f * 16;
        op[c] = (acc[mi][f][r] - mu) * rs * gamma[c] + beta[c];
      }
    }
}

extern "C" void kernel_launch(void* const* d_in, const int* in_sizes, int n_in,
                              void* d_out, int out_size, void* d_ws, size_t ws_size,
                              hipStream_t stream) {
  const float* x   = (const float*)d_in[0];  // [8,1024,8,512]
  const float* hw  = (const float*)d_in[1];  // [2,512,512]
  const float* hb  = (const float*)d_in[2];  // [2,512]
  const float* cw  = (const float*)d_in[3];  // [512,512]
  const float* cb  = (const float*)d_in[4];  // [512]
  const float* gam = (const float*)d_in[5];
  const float* bet = (const float*)d_in[6];
  float* out = (float*)d_out;

  char* ws = (char*)d_ws;
  short* gbf   = (short*)ws; ws += (size_t)NTOK * DD * 2;  // 8 MB
  short* w1t   = (short*)ws; ws += DD * DD * 2;
  short* w2b   = (short*)ws; ws += DD * DD * 2;
  short* wcb   = (short*)ws; ws += DD * DD * 2;
  short* w21t  = (short*)ws; ws += DD * DD * 2;
  short* wcomb = (short*)ws; ws += DD * DD * 2;
  float* tmpv  = (float*)ws; ws += DD * 4;
  float* cbias = (float*)ws; ws += DD * 4;

  const float* W1 = hw;
  const float* W2 = hw + DD * DD;
  const float* b1 = hb;
  const float* b2 = hb + DD;

  // big mandatory read first
  pool_kernel<<<2048, 256, 0, stream>>>(x, gbf);
  // weight prep chain (all tiny)
  casttr_kernel<<<256, 256, 0, stream>>>(W1, w1t);
  cast2_kernel<<<512, 256, 0, stream>>>(W2, cw, w2b, wcb);
  mv_kernel<<<128, 256, 0, stream>>>(W2, b1, b2, tmpv);       // tmpv = W2*b1+b2
  mv_kernel<<<128, 256, 0, stream>>>(cw, tmpv, cb, cbias);    // cbias = Wc*tmpv+cb
  wgemm_kernel<<<64, 256, 0, stream>>>(w1t, w2b, w21t);       // W21T[d,i]=W21[i,d]
  wgemm_kernel<<<64, 256, 0, stream>>>(wcb, w21t, wcomb);     // Wcomb[o,d]
  // fused GEMM + gelu + LayerNorm
  main_kernel<<<NTOK / 32, 256, 0, stream>>>(gbf, wcomb, cbias, gam, bet, out);
}

// Round 4
// 261.043 us; speedup vs baseline: 1.0732x; 1.0732x over previous
//
#include <hip/hip_runtime.h>
#include <hip/hip_bf16.h>
#include <math.h>

// HGNNExpertCoupler, algebraically collapsed:
//   all_pairs hypergraph => M = (6I+J)/14 doubly stochastic; mean-pool kills it:
//   out = LN(gelu( meanE(x) @ (Wc*W2*W1)^T + Wc*(W2*b1+b2)+cb ))
// 4 launches: prep1 {W1^T cast | W2/Wc cast | tmpv=W2*b1+b2}
//             prep2 {w21t = W1T x_NT W2 | cbias = Wc*tmpv+cb}
//             prep3 {wcomb = WcB x_NT w21t}
//             main  {pool(meanE) -> swizzled LDS -> MFMA GEMM -> gelu+LN}

#define DD 512
#define NTOK 8192  // B*L

typedef short s16x8 __attribute__((ext_vector_type(8)));
typedef short s16x4 __attribute__((ext_vector_type(4)));
typedef float f32x4 __attribute__((ext_vector_type(4)));

static __device__ __forceinline__ short f2bf(float x) {
  unsigned u = __builtin_bit_cast(unsigned, x);
  unsigned r = (u + 0x7fffu + ((u >> 16) & 1u)) >> 16;
  return (short)r;
}

// ---------- helpers reused across prep kernels ----------
static __device__ __forceinline__ void do_cast4(const float* __restrict__ src,
                                                short* __restrict__ dst, int i) {
  int j = i << 2;
  f32x4 v = *(const f32x4*)(src + j);
  s16x4 o;
  o[0] = f2bf(v[0]); o[1] = f2bf(v[1]); o[2] = f2bf(v[2]); o[3] = f2bf(v[3]);
  *(s16x4*)(dst + j) = o;
}

static __device__ __forceinline__ void do_mv(const float* __restrict__ M,
                                             const float* __restrict__ v,
                                             const float* __restrict__ add,
                                             float* __restrict__ outv,
                                             int gtid) {
  int w = gtid >> 6, l = gtid & 63;
  if (w >= DD) return;
  float s = 0.f;
  for (int k = l; k < DD; k += 64) s += M[(size_t)w * DD + k] * v[k];
#pragma unroll
  for (int m = 32; m; m >>= 1) s += __shfl_xor(s, m);
  if (l == 0) outv[w] = s + add[w];
}

// ---------- prep1: casttr(W1) [0,256) | cast W2,Wc [256,768) | mv1 [768,896)
__global__ __launch_bounds__(256) void prep1_kernel(
    const float* __restrict__ w1, const float* __restrict__ w2,
    const float* __restrict__ wc, const float* __restrict__ b1,
    const float* __restrict__ b2, short* __restrict__ w1t,
    short* __restrict__ w2b, short* __restrict__ wcb,
    float* __restrict__ tmpv) {
  int b = blockIdx.x, tid = threadIdx.x;
  if (b < 256) {  // transpose-cast W1 -> W1T bf16, 32x32 tiles
    __shared__ float t[32][33];
    int bx = b & 15, by = b >> 4;
    int tx = tid & 31, ty8 = tid >> 5;
    int r0 = by * 32, c0 = bx * 32;
#pragma unroll
    for (int j = 0; j < 4; ++j) {
      int r = ty8 * 4 + j;
      t[r][tx] = w1[(size_t)(r0 + r) * DD + c0 + tx];
    }
    __syncthreads();
#pragma unroll
    for (int j = 0; j < 4; ++j) {
      int r = ty8 * 4 + j;
      w1t[(size_t)(c0 + r) * DD + r0 + tx] = f2bf(t[tx][r]);
    }
  } else if (b < 768) {  // straight casts: 512 blocks, 131072 f32x4 chunks
    int i = (b - 256) * 256 + tid;  // [0, 131072)
    if (i < 65536) do_cast4(w2, w2b, i);
    else           do_cast4(wc, wcb, i - 65536);
  } else {  // tmpv = W2*b1 + b2 : 128 blocks = 512 waves
    do_mv(w2, b1, b2, tmpv, (b - 768) * 256 + tid);
  }
}

// -------- NT GEMM body (512^3): Out[m,n] = sum_k A[m,k]*B[n,k], 64 blocks ---
static __device__ __forceinline__ void do_wgemm(const short* __restrict__ A,
                                                const short* __restrict__ B,
                                                short* __restrict__ Out,
                                                int b, int tid) {
  int w = tid >> 6, l = tid & 63;
  int lr = l & 15, lg = l >> 4;
  int m0 = (b >> 3) * 64 + w * 16;
  int n0 = (b & 7) * 64;
  f32x4 acc[4] = {};
  const short* ap = A + (size_t)(m0 + lr) * DD + 8 * lg;
  const short* bp = B + (size_t)(n0 + lr) * DD + 8 * lg;
#pragma unroll
  for (int k0 = 0; k0 < DD; k0 += 32) {
    s16x8 a = *(const s16x8*)(ap + k0);
#pragma unroll
    for (int f = 0; f < 4; ++f) {
      s16x8 bb = *(const s16x8*)(bp + (size_t)f * 16 * DD + k0);
      acc[f] = __builtin_amdgcn_mfma_f32_16x16x32_bf16(a, bb, acc[f], 0, 0, 0);
    }
  }
#pragma unroll
  for (int f = 0; f < 4; ++f)
#pragma unroll
    for (int r = 0; r < 4; ++r)
      Out[(size_t)(m0 + lg * 4 + r) * DD + n0 + f * 16 + lr] = f2bf(acc[f][r]);
}

// ---------- prep2: wgemm1 [0,64) | mv2 [64,192) ----------
__global__ __launch_bounds__(256) void prep2_kernel(
    const short* __restrict__ w1t, const short* __restrict__ w2b,
    short* __restrict__ w21t, const float* __restrict__ wc,
    const float* __restrict__ tmpv, const float* __restrict__ cb,
    float* __restrict__ cbias) {
  int b = blockIdx.x, tid = threadIdx.x;
  if (b < 64) do_wgemm(w1t, w2b, w21t, b, tid);          // (W2*W1)^T
  else        do_mv(wc, tmpv, cb, cbias, (b - 64) * 256 + tid);
}

// ---------- prep3: wcomb = Wc x_NT w21t = Wc*W2*W1 (row-major [o][d]) -------
__global__ __launch_bounds__(256) void prep3_kernel(const short* __restrict__ wcb,
                                                    const short* __restrict__ w21t,
                                                    short* __restrict__ wcomb) {
  do_wgemm(wcb, w21t, wcomb, blockIdx.x, threadIdx.x);
}

// ---- main: pool 16 tokens (meanE of x) -> LDS bf16 -> GEMM -> gelu+LN ------
// 512 blocks x 16 tokens; 4 waves, wave tile 16x128. A XOR-swizzled in LDS.
__global__ __launch_bounds__(256) void main_kernel(
    const float* __restrict__ x, const short* __restrict__ wcomb,
    const float* __restrict__ cbias, const float* __restrict__ gamma,
    const float* __restrict__ beta, float* __restrict__ out) {
  __shared__ short As[16 * DD];    // 16 KB, XOR-swizzled rows
  __shared__ float red[16][4][2];  // per-row per-wave {sum, sumsq}
  int tid = threadIdx.x;
  int w = tid >> 6, l = tid & 63;
  int lr = l & 15, lg = l >> 4;
  int m0 = blockIdx.x * 16;

  // fused pool+stage: read x[(m0+n)][e][d], mean over e, bf16, swizzled write
  {
    const float* xb = x + (size_t)m0 * (8 * DD);
    char* ls = (char*)As;
#pragma unroll
    for (int j = 0; j < 8; ++j) {
      int i = tid + 256 * j;        // 2048 f32x4 outputs (16 rows x 128)
      int n = i >> 7;
      int d4 = (i & 127) << 2;
      const float* p = xb + n * (8 * DD) + d4;
      f32x4 s = {0.f, 0.f, 0.f, 0.f};
#pragma unroll
      for (int e = 0; e < 8; ++e) s += *(const f32x4*)(p + e * DD);
      s *= 0.125f;
      s16x4 o;
      o[0] = f2bf(s[0]); o[1] = f2bf(s[1]); o[2] = f2bf(s[2]); o[3] = f2bf(s[3]);
      int bo = d4 << 1;  // byte offset in 1024B row
      *(s16x4*)(ls + n * 1024 + (bo ^ ((n & 7) << 4))) = o;
    }
  }
  __syncthreads();

  f32x4 acc[8] = {};
  const short* bbase = wcomb + (size_t)(w * 128 + lr) * DD + 8 * lg;
  const char* lsc = (const char*)As;
  for (int k0 = 0; k0 < DD; k0 += 32) {
    int kb = (k0 + 8 * lg) * 2;
    s16x8 a = *(const s16x8*)(lsc + lr * 1024 + (kb ^ ((lr & 7) << 4)));
#pragma unroll
    for (int f = 0; f < 8; ++f) {
      s16x8 b = *(const s16x8*)(bbase + (size_t)f * 16 * DD + k0);
      acc[f] = __builtin_amdgcn_mfma_f32_16x16x32_bf16(a, b, acc[f], 0, 0, 0);
    }
  }

  // epilogue: +cbias, exact gelu, per-row LN over the 512 outs
  int cbase = w * 128 + lr;
  float s1[4] = {}, s2[4] = {};
#pragma unroll
  for (int f = 0; f < 8; ++f) {
    float cb = cbias[cbase + f * 16];
#pragma unroll
    for (int r = 0; r < 4; ++r) {
      float xx = acc[f][r] + cb;
      float z = 0.5f * xx * (1.0f + erff(xx * 0.70710678118f));
      acc[f][r] = z;
      s1[r] += z;
      s2[r] += z * z;
    }
  }
#pragma unroll
  for (int m = 1; m < 16; m <<= 1)
#pragma unroll
    for (int r = 0; r < 4; ++r) {
      s1[r] += __shfl_xor(s1[r], m);
      s2[r] += __shfl_xor(s2[r], m);
    }
  if (lr == 0) {
#pragma unroll
    for (int r = 0; r < 4; ++r) {
      int row = lg * 4 + r;
      red[row][w][0] = s1[r];
      red[row][w][1] = s2[r];
    }
  }
  __syncthreads();
#pragma unroll
  for (int r = 0; r < 4; ++r) {
    int row = lg * 4 + r;
    float t1 = red[row][0][0] + red[row][1][0] + red[row][2][0] + red[row][3][0];
    float t2 = red[row][0][1] + red[row][1][1] + red[row][2][1] + red[row][3][1];
    float mu = t1 * (1.0f / 512.0f);
    float var = t2 * (1.0f / 512.0f) - mu * mu;
    float rs = rsqrtf(var + 1e-5f);
    float* op = out + (size_t)(m0 + row) * DD;
#pragma unroll
    for (int f = 0; f < 8; ++f) {
      int c = cbase + f * 16;
      op[c] = (acc[f][r] - mu) * rs * gamma[c] + beta[c];
    }
  }
}

extern "C" void kernel_launch(void* const* d_in, const int* in_sizes, int n_in,
                              void* d_out, int out_size, void* d_ws, size_t ws_size,
                              hipStream_t stream) {
  const float* x   = (const float*)d_in[0];  // [8,1024,8,512]
  const float* hw  = (const float*)d_in[1];  // [2,512,512]
  const float* hb  = (const float*)d_in[2];  // [2,512]
  const float* cw  = (const float*)d_in[3];  // [512,512]
  const float* cb  = (const float*)d_in[4];  // [512]
  const float* gam = (const float*)d_in[5];
  const float* bet = (const float*)d_in[6];
  float* out = (float*)d_out;

  char* ws = (char*)d_ws;
  short* w1t   = (short*)ws; ws += DD * DD * 2;
  short* w2b   = (short*)ws; ws += DD * DD * 2;
  short* wcb   = (short*)ws; ws += DD * DD * 2;
  short* w21t  = (short*)ws; ws += DD * DD * 2;
  short* wcomb = (short*)ws; ws += DD * DD * 2;
  float* tmpv  = (float*)ws; ws += DD * 4;
  float* cbias = (float*)ws; ws += DD * 4;

  const float* W1 = hw;
  const float* W2 = hw + DD * DD;
  const float* b1 = hb;
  const float* b2 = hb + DD;

  prep1_kernel<<<896, 256, 0, stream>>>(W1, W2, cw, b1, b2, w1t, w2b, wcb, tmpv);
  prep2_kernel<<<192, 256, 0, stream>>>(w1t, w2b, w21t, cw, tmpv, cb, cbias);
  prep3_kernel<<<64, 256, 0, stream>>>(wcb, w21t, wcomb);
  main_kernel<<<NTOK / 16, 256, 0, stream>>>(x, wcomb, cbias, gam, bet, out);
}